// Round 1
// baseline (404.488 us; speedup 1.0000x reference)
//
#include <hip/hip_runtime.h>
#include <math.h>

// Problem constants (match reference)
static constexpr int Bn  = 256;   // batch
static constexpr int Dd  = 2048;  // feature dim
static constexpr int ATT = 512;   // attribute dim
static constexpr int Cc  = 1024;  // classes
// TEMP = 4.0 -> 1/TEMP = 0.25, TEMP^2 = 16 ; SCALE = 20.0

// ---------------- reductions (blockDim.x == 256 assumed) ----------------
__device__ __forceinline__ float wave_reduce_sum(float v) {
#pragma unroll
    for (int off = 32; off; off >>= 1) v += __shfl_down(v, off, 64);
    return v;
}
__device__ __forceinline__ float wave_reduce_max(float v) {
#pragma unroll
    for (int off = 32; off; off >>= 1) v = fmaxf(v, __shfl_down(v, off, 64));
    return v;
}
__device__ __forceinline__ float block_reduce_sum(float v) {
    __shared__ float sm_s[4];
    v = wave_reduce_sum(v);
    __syncthreads();                       // protect sm_s reuse across calls
    if ((threadIdx.x & 63) == 0) sm_s[threadIdx.x >> 6] = v;
    __syncthreads();
    return sm_s[0] + sm_s[1] + sm_s[2] + sm_s[3];
}
__device__ __forceinline__ float block_reduce_max(float v) {
    __shared__ float sm_m[4];
    v = wave_reduce_max(v);
    __syncthreads();
    if ((threadIdx.x & 63) == 0) sm_m[threadIdx.x >> 6] = v;
    __syncthreads();
    return fmaxf(fmaxf(sm_m[0], sm_m[1]), fmaxf(sm_m[2], sm_m[3]));
}

// ---------------- row-wise L2 normalize (block per row) ----------------
__global__ __launch_bounds__(256) void l2norm_rows(const float* __restrict__ in,
                                                   float* __restrict__ out, int ncols) {
    const int row = blockIdx.x;
    const float* r = in + (size_t)row * ncols;
    float ss = 0.f;
    for (int c = threadIdx.x; c < ncols; c += 256) { float v = r[c]; ss = fmaf(v, v, ss); }
    ss = block_reduce_sum(ss);
    const float s = 1.0f / fmaxf(sqrtf(ss), 1e-12f);
    float* o = out + (size_t)row * ncols;
    for (int c = threadIdx.x; c < ncols; c += 256) o[c] = r[c] * s;
}

// ---------------- tiled f32 GEMM, C[MxN] = alpha*(A[MxK] . B[NxK]^T + bias) --------
template <int BM, int BN, int BK>
__global__ __launch_bounds__(256) void gemm_nt(const float* __restrict__ A,
                                               const float* __restrict__ B,
                                               const float* __restrict__ bias,
                                               float* __restrict__ C,
                                               int M, int N, int K, float alpha) {
    __shared__ float As[BM][BK + 1];
    __shared__ float Bs[BN][BK + 1];
    const int tid = threadIdx.x;
    const int tx = tid & 15, ty = tid >> 4;       // 16x16 thread grid, 4x4 per thread
    const int row0 = blockIdx.y * BM, col0 = blockIdx.x * BN;
    float acc[4][4] = {};
    constexpr int F4 = BK / 4;                    // float4 per LDS row
    for (int k0 = 0; k0 < K; k0 += BK) {
#pragma unroll
        for (int t = tid; t < BM * F4; t += 256) {
            const int r = t / F4, fc = (t % F4) * 4;
            const float4 v = *(const float4*)(A + (size_t)(row0 + r) * K + k0 + fc);
            As[r][fc] = v.x; As[r][fc + 1] = v.y; As[r][fc + 2] = v.z; As[r][fc + 3] = v.w;
        }
#pragma unroll
        for (int t = tid; t < BN * F4; t += 256) {
            const int r = t / F4, fc = (t % F4) * 4;
            const float4 v = *(const float4*)(B + (size_t)(col0 + r) * K + k0 + fc);
            Bs[r][fc] = v.x; Bs[r][fc + 1] = v.y; Bs[r][fc + 2] = v.z; Bs[r][fc + 3] = v.w;
        }
        __syncthreads();
#pragma unroll
        for (int k = 0; k < BK; ++k) {
            float a[4], bv[4];
#pragma unroll
            for (int u = 0; u < 4; ++u) a[u] = As[ty * 4 + u][k];
#pragma unroll
            for (int u = 0; u < 4; ++u) bv[u] = Bs[tx * 4 + u][k];
#pragma unroll
            for (int u = 0; u < 4; ++u)
#pragma unroll
                for (int w = 0; w < 4; ++w) acc[u][w] = fmaf(a[u], bv[w], acc[u][w]);
        }
        __syncthreads();
    }
#pragma unroll
    for (int u = 0; u < 4; ++u) {
        const int r = row0 + ty * 4 + u;
#pragma unroll
        for (int w = 0; w < 4; ++w) {
            const int c = col0 + tx * 4 + w;
            const float v = acc[u][w] + (bias ? bias[c] : 0.0f);
            C[(size_t)r * N + c] = alpha * v;
        }
    }
}

// ---------------- softmax of logits/TEMP over C, produce P and negH ----------------
__global__ __launch_bounds__(256) void softmax_rows(const float* __restrict__ logits,
                                                    float* __restrict__ P,
                                                    float* __restrict__ negH) {
    const int i = blockIdx.x;
    const float* l = logits + (size_t)i * Cc;
    float lv[4];
    float lm = -1e30f;
#pragma unroll
    for (int k = 0; k < 4; ++k) {
        lv[k] = l[threadIdx.x + k * 256] * 0.25f;   // logits / TEMP
        lm = fmaxf(lm, lv[k]);
    }
    lm = block_reduce_max(lm);
    float se = 0.f;
#pragma unroll
    for (int k = 0; k < 4; ++k) se += expf(lv[k] - lm);
    se = block_reduce_sum(se);
    const float logZ = logf(se);
    float nh = 0.f;
    float* Pr = P + (size_t)i * Cc;
#pragma unroll
    for (int k = 0; k < 4; ++k) {
        const float lp = lv[k] - lm - logZ;
        const float p = expf(lp);
        Pr[threadIdx.x + k * 256] = p;
        nh = fmaf(p, lp, nh);
    }
    nh = block_reduce_sum(nh);
    if (threadIdx.x == 0) negH[i] = nh;
}

// ---------------- accumulator init ----------------
__global__ void init_acc(float* sumAcc, int* cnt) {
    *sumAcc = 0.0f;
    *cnt = 0;
}

// ---------------- build compacted list of masked pairs ----------------
__global__ __launch_bounds__(256) void build_pairs(const int* __restrict__ labels,
                                                   int2* __restrict__ pairs,
                                                   int* __restrict__ cnt) {
    for (int p = threadIdx.x; p < Bn * Bn; p += 256) {
        const int i = p >> 8, j = p & 255;
        if (j > i && labels[i] == labels[j]) {
            const int pos = atomicAdd(cnt, 1);
            pairs[pos] = make_int2(i, j);
        }
    }
}

// ---------------- JS over masked pairs ----------------
// JS_ij = 0.5*(negH_i + negH_j - sum_c (P_i+P_j)*log((P_i+P_j)/2))
__global__ __launch_bounds__(256) void pair_js(const float* __restrict__ P,
                                               const float* __restrict__ negH,
                                               const int2* __restrict__ pairs,
                                               const int* __restrict__ cnt,
                                               float* __restrict__ sumAcc) {
    const int n = *cnt;
    for (int w = blockIdx.x; w < n; w += gridDim.x) {
        const int2 pr = pairs[w];
        const float* Pi = P + (size_t)pr.x * Cc;
        const float* Pj = P + (size_t)pr.y * Cc;
        float s = 0.f;
        for (int c = threadIdx.x; c < Cc; c += 256) {
            const float t = Pi[c] + Pj[c];
            s = fmaf(t, logf(0.5f * t), s);
        }
        s = block_reduce_sum(s);
        if (threadIdx.x == 0)
            atomicAdd(sumAcc, 0.5f * (negH[pr.x] + negH[pr.y] - s));
    }
}

// ---------------- finalize ----------------
__global__ void finalize(const float* sumAcc, const int* cnt, float* out) {
    const int n = *cnt;
    out[0] = (n == 0) ? 0.0f : (*sumAcc / (float)n) * 16.0f;   // * TEMP^2
}

extern "C" void kernel_launch(void* const* d_in, const int* in_sizes, int n_in,
                              void* d_out, int out_size, void* d_ws, size_t ws_size,
                              hipStream_t stream) {
    const float* x      = (const float*)d_in[0];  // [256, 2048]
    const int*   labels = (const int*)d_in[1];    // [256]
    const float* W      = (const float*)d_in[2];  // [512, 2048]
    const float* bias   = (const float*)d_in[3];  // [512]
    const float* seen   = (const float*)d_in[4];  // [1024, 512]
    float* out = (float*)d_out;

    char* ws = (char*)d_ws;
    float* sa     = (float*)(ws);                         // 1024*512 f32 = 2 MB
    float* ya     = (float*)(ws + (2u << 20));            // 256*512  f32 = 512 KB
    float* logits = (float*)(ws + (2u << 20) + (512u << 10)); // 256*1024 f32 = 1 MB
    float* P      = (float*)(ws + (3u << 20) + (512u << 10)); // 256*1024 f32 = 1 MB
    float* negH   = (float*)(ws + (4u << 20) + (512u << 10)); // 256 f32
    float* sumAcc = negH + Bn;
    int*   cnt    = (int*)(sumAcc + 1);
    int2*  pairs  = (int2*)(ws + (5u << 20));             // up to 32640 int2 = 256 KB

    init_acc<<<1, 1, 0, stream>>>(sumAcc, cnt);
    l2norm_rows<<<Cc, 256, 0, stream>>>(seen, sa, ATT);
    gemm_nt<64, 64, 32><<<dim3(ATT / 64, Bn / 64), 256, 0, stream>>>(
        x, W, bias, ya, Bn, ATT, Dd, 1.0f);
    l2norm_rows<<<Bn, 256, 0, stream>>>(ya, ya, ATT);
    gemm_nt<64, 64, 32><<<dim3(Cc / 64, Bn / 64), 256, 0, stream>>>(
        ya, sa, nullptr, logits, Bn, Cc, ATT, 20.0f);
    softmax_rows<<<Bn, 256, 0, stream>>>(logits, P, negH);
    build_pairs<<<1, 256, 0, stream>>>(labels, pairs, cnt);
    pair_js<<<1024, 256, 0, stream>>>(P, negH, pairs, cnt, sumAcc);
    finalize<<<1, 1, 0, stream>>>(sumAcc, cnt, out);
}

// Round 2
// 159.179 us; speedup vs baseline: 2.5411x; 2.5411x over previous
//
#include <hip/hip_runtime.h>
#include <math.h>

// Problem constants (match reference)
static constexpr int Bn  = 256;   // batch
static constexpr int Dd  = 2048;  // feature dim
static constexpr int ATT = 512;   // attribute dim
static constexpr int Cc  = 1024;  // classes
static constexpr int SK1 = 16;    // split-K slices for GEMM1 (K=2048, chunk 128)
static constexpr int SK2 = 8;     // split-K slices for GEMM2 (K=512,  chunk 64)
// TEMP = 4.0 -> 1/TEMP = 0.25, TEMP^2 = 16 ; SCALE = 20.0 ; SCALE/TEMP = 5

// ---------------- reductions (blockDim.x == 256 assumed) ----------------
__device__ __forceinline__ float wave_reduce_sum(float v) {
#pragma unroll
    for (int off = 32; off; off >>= 1) v += __shfl_down(v, off, 64);
    return v;
}
__device__ __forceinline__ float wave_reduce_max(float v) {
#pragma unroll
    for (int off = 32; off; off >>= 1) v = fmaxf(v, __shfl_down(v, off, 64));
    return v;
}
__device__ __forceinline__ float block_reduce_sum(float v) {
    __shared__ float sm_s[4];
    v = wave_reduce_sum(v);
    __syncthreads();
    if ((threadIdx.x & 63) == 0) sm_s[threadIdx.x >> 6] = v;
    __syncthreads();
    return sm_s[0] + sm_s[1] + sm_s[2] + sm_s[3];
}
__device__ __forceinline__ float block_reduce_max(float v) {
    __shared__ float sm_m[4];
    v = wave_reduce_max(v);
    __syncthreads();
    if ((threadIdx.x & 63) == 0) sm_m[threadIdx.x >> 6] = v;
    __syncthreads();
    return fmaxf(fmaxf(sm_m[0], sm_m[1]), fmaxf(sm_m[2], sm_m[3]));
}

// ---------------- row-wise L2 normalize (block per row) ----------------
__global__ __launch_bounds__(256) void l2norm_rows(const float* __restrict__ in,
                                                   float* __restrict__ out, int ncols) {
    const int row = blockIdx.x;
    const float* r = in + (size_t)row * ncols;
    float ss = 0.f;
    for (int c = threadIdx.x; c < ncols; c += 256) { float v = r[c]; ss = fmaf(v, v, ss); }
    ss = block_reduce_sum(ss);
    const float s = 1.0f / fmaxf(sqrtf(ss), 1e-12f);
    float* o = out + (size_t)row * ncols;
    for (int c = threadIdx.x; c < ncols; c += 256) o[c] = r[c] * s;
}

// ------- split-K tiled f32 GEMM (NT): part[z][M][N] += A[M,K-chunk] . B[N,K-chunk]^T
// LDS tiles stored K-major so fragment reads are ds_read_b128.
template <int BM, int BN, int BK, int KC>
__global__ __launch_bounds__(256) void gemm_nt_splitk(const float* __restrict__ A,
                                                      const float* __restrict__ B,
                                                      float* __restrict__ part,
                                                      int M, int N, int K) {
    __shared__ float As[BK][BM + 4];
    __shared__ float Bs[BK][BN + 4];
    const int tid = threadIdx.x;
    const int tx = tid & 15, ty = tid >> 4;       // 16x16 threads, 4x4 per thread
    const int row0 = blockIdx.y * BM, col0 = blockIdx.x * BN;
    const int kbase = blockIdx.z * KC;
    float acc[4][4] = {};
    constexpr int F4 = BK / 4;                    // float4 per tile row
    for (int k0 = kbase; k0 < kbase + KC; k0 += BK) {
#pragma unroll
        for (int t = tid; t < BM * F4; t += 256) {
            const int r = t / F4, c4 = (t % F4) * 4;
            const float4 v = *(const float4*)(A + (size_t)(row0 + r) * K + k0 + c4);
            As[c4 + 0][r] = v.x; As[c4 + 1][r] = v.y; As[c4 + 2][r] = v.z; As[c4 + 3][r] = v.w;
        }
#pragma unroll
        for (int t = tid; t < BN * F4; t += 256) {
            const int r = t / F4, c4 = (t % F4) * 4;
            const float4 v = *(const float4*)(B + (size_t)(col0 + r) * K + k0 + c4);
            Bs[c4 + 0][r] = v.x; Bs[c4 + 1][r] = v.y; Bs[c4 + 2][r] = v.z; Bs[c4 + 3][r] = v.w;
        }
        __syncthreads();
#pragma unroll
        for (int k = 0; k < BK; ++k) {
            const float4 a4 = *(const float4*)&As[k][ty * 4];
            const float4 b4 = *(const float4*)&Bs[k][tx * 4];
            const float a[4] = {a4.x, a4.y, a4.z, a4.w};
            const float b[4] = {b4.x, b4.y, b4.z, b4.w};
#pragma unroll
            for (int u = 0; u < 4; ++u)
#pragma unroll
                for (int w = 0; w < 4; ++w) acc[u][w] = fmaf(a[u], b[w], acc[u][w]);
        }
        __syncthreads();
    }
    float* dst = part + (size_t)blockIdx.z * M * N;
#pragma unroll
    for (int u = 0; u < 4; ++u) {
        const int r = row0 + ty * 4 + u;
#pragma unroll
        for (int w = 0; w < 4; ++w) {
            const int c = col0 + tx * 4 + w;
            dst[(size_t)r * N + c] = acc[u][w];
        }
    }
}

// ------- fused: ya[m] = l2norm(bias + sum_s part1[s][m][:])  (block per row, N=512)
__global__ __launch_bounds__(256) void reduce_bias_l2norm(const float* __restrict__ part,
                                                          const float* __restrict__ bias,
                                                          float* __restrict__ ya) {
    const int m = blockIdx.x;
    float v[2];
    float ss = 0.f;
#pragma unroll
    for (int u = 0; u < 2; ++u) {
        const int c = threadIdx.x + u * 256;
        float s = bias[c];
#pragma unroll
        for (int z = 0; z < SK1; ++z)
            s += part[(size_t)z * Bn * ATT + (size_t)m * ATT + c];
        v[u] = s;
        ss = fmaf(s, s, ss);
    }
    ss = block_reduce_sum(ss);
    const float sc = 1.0f / fmaxf(sqrtf(ss), 1e-12f);
#pragma unroll
    for (int u = 0; u < 2; ++u)
        ya[(size_t)m * ATT + threadIdx.x + u * 256] = v[u] * sc;
}

// ------- fused: logits = 5 * sum_s part2 ; softmax -> P, negH (block per row, C=1024)
__global__ __launch_bounds__(256) void reduce_softmax(const float* __restrict__ part,
                                                      float* __restrict__ P,
                                                      float* __restrict__ negH) {
    const int i = blockIdx.x;
    float lv[4];
    float lm = -1e30f;
#pragma unroll
    for (int k = 0; k < 4; ++k) {
        const int c = threadIdx.x + k * 256;
        float s = 0.f;
#pragma unroll
        for (int z = 0; z < SK2; ++z)
            s += part[(size_t)z * Bn * Cc + (size_t)i * Cc + c];
        lv[k] = s * 5.0f;                      // (SCALE=20 / TEMP=4)
        lm = fmaxf(lm, lv[k]);
    }
    lm = block_reduce_max(lm);
    float se = 0.f;
#pragma unroll
    for (int k = 0; k < 4; ++k) se += expf(lv[k] - lm);
    se = block_reduce_sum(se);
    const float logZ = logf(se);
    float nh = 0.f;
    float* Pr = P + (size_t)i * Cc;
#pragma unroll
    for (int k = 0; k < 4; ++k) {
        const float lp = lv[k] - lm - logZ;
        const float p = expf(lp);
        Pr[threadIdx.x + k * 256] = p;
        nh = fmaf(p, lp, nh);
    }
    nh = block_reduce_sum(nh);
    if (threadIdx.x == 0) negH[i] = nh;
}

// ---------------- accumulator init ----------------
__global__ void init_acc(float* sumAcc, int* cnt) {
    *sumAcc = 0.0f;
    *cnt = 0;
}

// ---------------- build compacted list of masked pairs ----------------
__global__ __launch_bounds__(256) void build_pairs(const int* __restrict__ labels,
                                                   int2* __restrict__ pairs,
                                                   int* __restrict__ cnt) {
    for (int p = threadIdx.x; p < Bn * Bn; p += 256) {
        const int i = p >> 8, j = p & 255;
        if (j > i && labels[i] == labels[j]) {
            const int pos = atomicAdd(cnt, 1);
            pairs[pos] = make_int2(i, j);
        }
    }
}

// ---------------- JS over masked pairs ----------------
// JS_ij = 0.5*(negH_i + negH_j - sum_c (P_i+P_j)*log((P_i+P_j)/2))
__global__ __launch_bounds__(256) void pair_js(const float* __restrict__ P,
                                               const float* __restrict__ negH,
                                               const int2* __restrict__ pairs,
                                               const int* __restrict__ cnt,
                                               float* __restrict__ sumAcc) {
    const int n = *cnt;
    for (int w = blockIdx.x; w < n; w += gridDim.x) {
        const int2 pr = pairs[w];
        const float* Pi = P + (size_t)pr.x * Cc;
        const float* Pj = P + (size_t)pr.y * Cc;
        float s = 0.f;
        for (int c = threadIdx.x; c < Cc; c += 256) {
            const float t = Pi[c] + Pj[c];
            s = fmaf(t, logf(0.5f * t), s);
        }
        s = block_reduce_sum(s);
        if (threadIdx.x == 0)
            atomicAdd(sumAcc, 0.5f * (negH[pr.x] + negH[pr.y] - s));
    }
}

// ---------------- finalize ----------------
__global__ void finalize(const float* sumAcc, const int* cnt, float* out) {
    const int n = *cnt;
    out[0] = (n == 0) ? 0.0f : (*sumAcc / (float)n) * 16.0f;   // * TEMP^2
}

extern "C" void kernel_launch(void* const* d_in, const int* in_sizes, int n_in,
                              void* d_out, int out_size, void* d_ws, size_t ws_size,
                              hipStream_t stream) {
    const float* x      = (const float*)d_in[0];  // [256, 2048]
    const int*   labels = (const int*)d_in[1];    // [256]
    const float* W      = (const float*)d_in[2];  // [512, 2048]
    const float* bias   = (const float*)d_in[3];  // [512]
    const float* seen   = (const float*)d_in[4];  // [1024, 512]
    float* out = (float*)d_out;

    char* ws = (char*)d_ws;
    // 8 MB split-K partial region, reused by GEMM1 (16x256x512) then GEMM2 (8x256x1024)
    float* part   = (float*)(ws);                         // 8 MB
    float* sa     = (float*)(ws + (8u << 20));            // 1024*512 f32 = 2 MB
    float* ya     = (float*)(ws + (10u << 20));           // 256*512  f32 = 512 KB
    float* P      = (float*)(ws + (10u << 20) + (512u << 10)); // 256*1024 f32 = 1 MB
    float* negH   = (float*)(ws + (11u << 20) + (512u << 10)); // 256 f32
    float* sumAcc = negH + Bn;
    int*   cnt    = (int*)(sumAcc + 1);
    int2*  pairs  = (int2*)(ws + (12u << 20));            // up to 32640 int2 = 256 KB

    init_acc<<<1, 1, 0, stream>>>(sumAcc, cnt);
    l2norm_rows<<<Cc, 256, 0, stream>>>(seen, sa, ATT);
    // GEMM1: y = x . W^T   (M=256, N=512, K=2048), split-K 16 (chunk 128)
    gemm_nt_splitk<64, 64, 32, 128><<<dim3(ATT / 64, Bn / 64, SK1), 256, 0, stream>>>(
        x, W, part, Bn, ATT, Dd);
    reduce_bias_l2norm<<<Bn, 256, 0, stream>>>(part, bias, ya);
    // GEMM2: logits_raw = ya . sa^T (M=256, N=1024, K=512), split-K 8 (chunk 64)
    gemm_nt_splitk<64, 64, 32, 64><<<dim3(Cc / 64, Bn / 64, SK2), 256, 0, stream>>>(
        ya, sa, part, Bn, Cc, ATT);
    reduce_softmax<<<Bn, 256, 0, stream>>>(part, P, negH);
    build_pairs<<<1, 256, 0, stream>>>(labels, pairs, cnt);
    pair_js<<<1024, 256, 0, stream>>>(P, negH, pairs, cnt, sumAcc);
    finalize<<<1, 1, 0, stream>>>(sumAcc, cnt, out);
}

// Round 3
// 69.771 us; speedup vs baseline: 5.7974x; 2.2815x over previous
//
#include <hip/hip_runtime.h>
#include <math.h>

// Problem constants (match reference)
static constexpr int Bn  = 256;   // batch
static constexpr int Dd  = 2048;  // feature dim
static constexpr int ATT = 512;   // attribute dim
static constexpr int Cc  = 1024;  // classes
static constexpr int SK1 = 16;    // split-K slices for GEMM1 (K=2048, chunk 128)
static constexpr int SK2 = 8;     // split-K slices for GEMM2 (K=512,  chunk 64)
// TEMP = 4.0 -> 1/TEMP = 0.25, TEMP^2 = 16 ; SCALE = 20.0 ; SCALE/TEMP = 5

// ---------------- reductions (blockDim.x == 256 assumed) ----------------
__device__ __forceinline__ float wave_reduce_sum(float v) {
#pragma unroll
    for (int off = 32; off; off >>= 1) v += __shfl_down(v, off, 64);
    return v;
}
__device__ __forceinline__ float wave_reduce_max(float v) {
#pragma unroll
    for (int off = 32; off; off >>= 1) v = fmaxf(v, __shfl_down(v, off, 64));
    return v;
}
__device__ __forceinline__ float block_reduce_sum(float v) {
    __shared__ float sm_s[4];
    v = wave_reduce_sum(v);
    __syncthreads();
    if ((threadIdx.x & 63) == 0) sm_s[threadIdx.x >> 6] = v;
    __syncthreads();
    return sm_s[0] + sm_s[1] + sm_s[2] + sm_s[3];
}
__device__ __forceinline__ float block_reduce_max(float v) {
    __shared__ float sm_m[4];
    v = wave_reduce_max(v);
    __syncthreads();
    if ((threadIdx.x & 63) == 0) sm_m[threadIdx.x >> 6] = v;
    __syncthreads();
    return fmaxf(fmaxf(sm_m[0], sm_m[1]), fmaxf(sm_m[2], sm_m[3]));
}

// ---------------- row-wise L2 normalize (block per row) ----------------
__global__ __launch_bounds__(256) void l2norm_rows(const float* __restrict__ in,
                                                   float* __restrict__ out, int ncols) {
    const int row = blockIdx.x;
    const float* r = in + (size_t)row * ncols;
    float ss = 0.f;
    for (int c = threadIdx.x; c < ncols; c += 256) { float v = r[c]; ss = fmaf(v, v, ss); }
    ss = block_reduce_sum(ss);
    const float s = 1.0f / fmaxf(sqrtf(ss), 1e-12f);
    float* o = out + (size_t)row * ncols;
    for (int c = threadIdx.x; c < ncols; c += 256) o[c] = r[c] * s;
}

// ------- split-K tiled f32 GEMM (NT): part[z][M][N] = A[M,K-chunk] . B[N,K-chunk]^T
// LDS tiles stored K-major so fragment reads are ds_read_b128.
template <int BM, int BN, int BK, int KC>
__global__ __launch_bounds__(256) void gemm_nt_splitk(const float* __restrict__ A,
                                                      const float* __restrict__ B,
                                                      float* __restrict__ part,
                                                      int M, int N, int K) {
    __shared__ float As[BK][BM + 4];
    __shared__ float Bs[BK][BN + 4];
    const int tid = threadIdx.x;
    const int tx = tid & 15, ty = tid >> 4;       // 16x16 threads, 4x4 per thread
    const int row0 = blockIdx.y * BM, col0 = blockIdx.x * BN;
    const int kbase = blockIdx.z * KC;
    float acc[4][4] = {};
    constexpr int F4 = BK / 4;                    // float4 per tile row
    for (int k0 = kbase; k0 < kbase + KC; k0 += BK) {
#pragma unroll
        for (int t = tid; t < BM * F4; t += 256) {
            const int r = t / F4, c4 = (t % F4) * 4;
            const float4 v = *(const float4*)(A + (size_t)(row0 + r) * K + k0 + c4);
            As[c4 + 0][r] = v.x; As[c4 + 1][r] = v.y; As[c4 + 2][r] = v.z; As[c4 + 3][r] = v.w;
        }
#pragma unroll
        for (int t = tid; t < BN * F4; t += 256) {
            const int r = t / F4, c4 = (t % F4) * 4;
            const float4 v = *(const float4*)(B + (size_t)(col0 + r) * K + k0 + c4);
            Bs[c4 + 0][r] = v.x; Bs[c4 + 1][r] = v.y; Bs[c4 + 2][r] = v.z; Bs[c4 + 3][r] = v.w;
        }
        __syncthreads();
#pragma unroll
        for (int k = 0; k < BK; ++k) {
            const float4 a4 = *(const float4*)&As[k][ty * 4];
            const float4 b4 = *(const float4*)&Bs[k][tx * 4];
            const float a[4] = {a4.x, a4.y, a4.z, a4.w};
            const float b[4] = {b4.x, b4.y, b4.z, b4.w};
#pragma unroll
            for (int u = 0; u < 4; ++u)
#pragma unroll
                for (int w = 0; w < 4; ++w) acc[u][w] = fmaf(a[u], b[w], acc[u][w]);
        }
        __syncthreads();
    }
    float* dst = part + (size_t)blockIdx.z * M * N;
#pragma unroll
    for (int u = 0; u < 4; ++u) {
        const int r = row0 + ty * 4 + u;
#pragma unroll
        for (int w = 0; w < 4; ++w) {
            const int c = col0 + tx * 4 + w;
            dst[(size_t)r * N + c] = acc[u][w];
        }
    }
}

// ------- fused: ya[m] = l2norm(bias + sum_s part1[s][m][:])  (block per row, N=512)
__global__ __launch_bounds__(256) void reduce_bias_l2norm(const float* __restrict__ part,
                                                          const float* __restrict__ bias,
                                                          float* __restrict__ ya) {
    const int m = blockIdx.x;
    float v[2];
    float ss = 0.f;
#pragma unroll
    for (int u = 0; u < 2; ++u) {
        const int c = threadIdx.x + u * 256;
        float s = bias[c];
#pragma unroll
        for (int z = 0; z < SK1; ++z)
            s += part[(size_t)z * Bn * ATT + (size_t)m * ATT + c];
        v[u] = s;
        ss = fmaf(s, s, ss);
    }
    ss = block_reduce_sum(ss);
    const float sc = 1.0f / fmaxf(sqrtf(ss), 1e-12f);
#pragma unroll
    for (int u = 0; u < 2; ++u)
        ya[(size_t)m * ATT + threadIdx.x + u * 256] = v[u] * sc;
}

// ------- fused: logits = 5 * sum_s part2 ; softmax -> P, negH (block per row, C=1024)
__global__ __launch_bounds__(256) void reduce_softmax(const float* __restrict__ part,
                                                      float* __restrict__ P,
                                                      float* __restrict__ negH) {
    const int i = blockIdx.x;
    float lv[4];
    float lm = -1e30f;
#pragma unroll
    for (int k = 0; k < 4; ++k) {
        const int c = threadIdx.x + k * 256;
        float s = 0.f;
#pragma unroll
        for (int z = 0; z < SK2; ++z)
            s += part[(size_t)z * Bn * Cc + (size_t)i * Cc + c];
        lv[k] = s * 5.0f;                      // (SCALE=20 / TEMP=4)
        lm = fmaxf(lm, lv[k]);
    }
    lm = block_reduce_max(lm);
    float se = 0.f;
#pragma unroll
    for (int k = 0; k < 4; ++k) se += expf(lv[k] - lm);
    se = block_reduce_sum(se);
    const float logZ = logf(se);
    float nh = 0.f;
    float* Pr = P + (size_t)i * Cc;
#pragma unroll
    for (int k = 0; k < 4; ++k) {
        const float lp = lv[k] - lm - logZ;
        const float p = expf(lp);
        Pr[threadIdx.x + k * 256] = p;
        nh = fmaf(p, lp, nh);
    }
    nh = block_reduce_sum(nh);
    if (threadIdx.x == 0) negH[i] = nh;
}

// ---------------- JS over masked pairs, no pair list, no atomics ----------------
// Block i: stage labels in LDS, hold P_i in regs, loop j>i with lbl[j]==lbl[i].
// JS_ij = 0.5*(negH_i + negH_j - sum_c (P_i+P_j)*log((P_i+P_j)/2))
__global__ __launch_bounds__(256) void pair_js_direct(const float* __restrict__ P,
                                                      const float* __restrict__ negH,
                                                      const int* __restrict__ labels,
                                                      float* __restrict__ pairSum,
                                                      float* __restrict__ pairCnt) {
    const int i = blockIdx.x;
    __shared__ int lbl[Bn];
    for (int t = threadIdx.x; t < Bn; t += 256) lbl[t] = labels[t];
    __syncthreads();
    const int li = lbl[i];

    const float* Pi = P + (size_t)i * Cc;
    float pi[4];
#pragma unroll
    for (int k = 0; k < 4; ++k) pi[k] = Pi[threadIdx.x + k * 256];
    const float nhi = negH[i];

    float sum = 0.f, cnt = 0.f;
    for (int j = i + 1; j < Bn; ++j) {
        if (lbl[j] != li) continue;            // uniform across block
        const float* Pj = P + (size_t)j * Cc;
        float s = 0.f;
#pragma unroll
        for (int k = 0; k < 4; ++k) {
            const float t = pi[k] + Pj[threadIdx.x + k * 256];
            s = fmaf(t, logf(0.5f * t), s);
        }
        s = block_reduce_sum(s);
        if (threadIdx.x == 0) {
            sum += 0.5f * (nhi + negH[j] - s);
            cnt += 1.0f;
        }
    }
    if (threadIdx.x == 0) { pairSum[i] = sum; pairCnt[i] = cnt; }
}

// ---------------- finalize: reduce per-row partials ----------------
__global__ __launch_bounds__(256) void finalize(const float* __restrict__ pairSum,
                                                const float* __restrict__ pairCnt,
                                                float* __restrict__ out) {
    const float s = block_reduce_sum(pairSum[threadIdx.x]);
    __syncthreads();
    const float c = block_reduce_sum(pairCnt[threadIdx.x]);
    if (threadIdx.x == 0)
        out[0] = (c == 0.0f) ? 0.0f : (s / c) * 16.0f;   // * TEMP^2
}

extern "C" void kernel_launch(void* const* d_in, const int* in_sizes, int n_in,
                              void* d_out, int out_size, void* d_ws, size_t ws_size,
                              hipStream_t stream) {
    const float* x      = (const float*)d_in[0];  // [256, 2048]
    const int*   labels = (const int*)d_in[1];    // [256]
    const float* W      = (const float*)d_in[2];  // [512, 2048]
    const float* bias   = (const float*)d_in[3];  // [512]
    const float* seen   = (const float*)d_in[4];  // [1024, 512]
    float* out = (float*)d_out;

    char* ws = (char*)d_ws;
    // 8 MB split-K partial region, reused by GEMM1 (16x256x512) then GEMM2 (8x256x1024)
    float* part    = (float*)(ws);                         // 8 MB
    float* sa      = (float*)(ws + (8u << 20));            // 1024*512 f32 = 2 MB
    float* ya      = (float*)(ws + (10u << 20));           // 256*512  f32 = 512 KB
    float* P       = (float*)(ws + (10u << 20) + (512u << 10)); // 256*1024 f32 = 1 MB
    float* negH    = (float*)(ws + (11u << 20) + (512u << 10)); // 256 f32
    float* pairSum = negH + Bn;                            // 256 f32
    float* pairCnt = pairSum + Bn;                         // 256 f32

    l2norm_rows<<<Cc, 256, 0, stream>>>(seen, sa, ATT);
    // GEMM1: y = x . W^T   (M=256, N=512, K=2048), split-K 16 (chunk 128)
    gemm_nt_splitk<64, 64, 32, 128><<<dim3(ATT / 64, Bn / 64, SK1), 256, 0, stream>>>(
        x, W, part, Bn, ATT, Dd);
    reduce_bias_l2norm<<<Bn, 256, 0, stream>>>(part, bias, ya);
    // GEMM2: logits_raw = ya . sa^T (M=256, N=1024, K=512), split-K 8 (chunk 64)
    gemm_nt_splitk<64, 64, 32, 64><<<dim3(Cc / 64, Bn / 64, SK2), 256, 0, stream>>>(
        ya, sa, part, Bn, Cc, ATT);
    reduce_softmax<<<Bn, 256, 0, stream>>>(part, P, negH);
    pair_js_direct<<<Bn, 256, 0, stream>>>(P, negH, labels, pairSum, pairCnt);
    finalize<<<1, 256, 0, stream>>>(pairSum, pairCnt, out);
}